// Round 1
// baseline (914.313 us; speedup 1.0000x reference)
//
#include <hip/hip_runtime.h>
#include <math.h>

// TopExpertsRouter on MI355X (gfx950)
// x: [16384, 4096] fp32, W: [64, 4096] fp32
// out (concat, fp32): top_idx [N,8] (as float values), weights [N,8], probs [N,64]
//
// Phase 1 (router_gemm): D split into nchunks ranges; grid = (N/256)*nchunks
// blocks so all 256 CUs are busy (thread=token alone gives only 64 blocks).
// Each thread holds 64 fp32 accumulators; W is indexed wave-uniformly so the
// compiler emits scalar s_loads -> inner loop is almost pure v_fmac_f32.
// Partials laid out [chunk][expert][token] so both the store here and the
// load in phase 2 are fully coalesced (token innermost).
//
// Phase 2 (router_finish): deterministic fixed-order reduction over chunks,
// softmax (expf for accuracy), iterative top-8 argmax with strict '>' so ties
// break to the lowest index (matches jax.lax.top_k). Masking uses static
// per-element compares so l[64] stays in registers (no scratch spill from
// dynamic indexing).

constexpr int D = 4096;
constexpr int E = 64;
constexpr int K = 8;

__global__ __launch_bounds__(256) void router_gemm(
    const float* __restrict__ x, const float* __restrict__ W,
    float* __restrict__ partial, int ntok, int dlen, int ntiles)
{
    const int tile  = blockIdx.x % ntiles;
    const int chunk = blockIdx.x / ntiles;
    const int n  = tile * 256 + threadIdx.x;
    const int d0 = chunk * dlen;

    float acc[E];
#pragma unroll
    for (int e = 0; e < E; ++e) acc[e] = 0.f;

    const float* xp  = x + (size_t)n * D + d0;
    const float* wp0 = W + d0;

    for (int d = 0; d < dlen; d += 4) {
        const float4 xv = *reinterpret_cast<const float4*>(xp + d);
#pragma unroll
        for (int e = 0; e < E; ++e) {
            const float* wp = wp0 + (size_t)e * D + d;  // wave-uniform -> s_load
            float a = acc[e];
            a = fmaf(xv.x, wp[0], a);
            a = fmaf(xv.y, wp[1], a);
            a = fmaf(xv.z, wp[2], a);
            a = fmaf(xv.w, wp[3], a);
            acc[e] = a;
        }
    }

    float* op = partial + (size_t)chunk * E * ntok + n;
#pragma unroll
    for (int e = 0; e < E; ++e) op[(size_t)e * ntok] = acc[e];  // coalesced
}

__global__ __launch_bounds__(64) void router_finish(
    const float* __restrict__ partial, float* __restrict__ out,
    int ntok, int nchunks)
{
    const int n = blockIdx.x * 64 + threadIdx.x;

    float l[E];
    {
        const float* p = partial + n;
#pragma unroll
        for (int e = 0; e < E; ++e) l[e] = p[(size_t)e * ntok];
    }
    for (int c = 1; c < nchunks; ++c) {
        const float* pc = partial + ((size_t)c * E) * ntok + n;
#pragma unroll
        for (int e = 0; e < E; ++e) l[e] += pc[(size_t)e * ntok];
    }

    // softmax
    float m = l[0];
#pragma unroll
    for (int e = 1; e < E; ++e) m = fmaxf(m, l[e]);
    float sum = 0.f;
#pragma unroll
    for (int e = 0; e < E; ++e) { l[e] = expf(l[e] - m); sum += l[e]; }
    const float inv = 1.f / sum;
#pragma unroll
    for (int e = 0; e < E; ++e) l[e] *= inv;

    // write probs [N, 64]
    float* probs = out + (size_t)ntok * 2 * K + (size_t)n * E;
#pragma unroll
    for (int e = 0; e < E; e += 4) {
        float4 v = make_float4(l[e], l[e + 1], l[e + 2], l[e + 3]);
        *reinterpret_cast<float4*>(probs + e) = v;
    }

    // top-8: iterative argmax, strict '>' => lowest index wins ties
    float vals[K];
    int   idxs[K];
    float ts = 0.f;
    for (int k = 0; k < K; ++k) {
        float best = -1.f;
        int   bi   = 0;
#pragma unroll
        for (int e = 0; e < E; ++e) {
            if (l[e] > best) { best = l[e]; bi = e; }
        }
        vals[k] = best;
        idxs[k] = bi;
        ts += best;
#pragma unroll
        for (int e = 0; e < E; ++e) {        // static-index mask, stays in regs
            if (e == bi) l[e] = -1.f;
        }
    }
    const float winv = 1.f / (ts + 1e-9f);

    float* oi = out + (size_t)n * K;
    float* ow = out + (size_t)ntok * K + (size_t)n * K;
#pragma unroll
    for (int k = 0; k < K; ++k) {
        oi[k] = (float)idxs[k];
        ow[k] = vals[k] * winv;
    }
}

extern "C" void kernel_launch(void* const* d_in, const int* in_sizes, int n_in,
                              void* d_out, int out_size, void* d_ws, size_t ws_size,
                              hipStream_t stream)
{
    const float* x = (const float*)d_in[0];
    const float* W = (const float*)d_in[1];
    float* out = (float*)d_out;

    const int ntok = in_sizes[0] / D;  // 16384

    // partial buffer: nchunks * E * ntok fp32; shrink if ws is small
    int nchunks = 8;
    while (nchunks > 1 &&
           (size_t)nchunks * E * (size_t)ntok * sizeof(float) > ws_size)
        nchunks >>= 1;
    const int dlen   = D / nchunks;
    const int ntiles = ntok / 256;

    float* partial = (float*)d_ws;

    hipLaunchKernelGGL(router_gemm, dim3(ntiles * nchunks), dim3(256), 0, stream,
                       x, W, partial, ntok, dlen, ntiles);
    hipLaunchKernelGGL(router_finish, dim3(ntok / 64), dim3(64), 0, stream,
                       partial, out, ntok, nchunks);
}